// Round 2
// baseline (314.830 us; speedup 1.0000x reference)
//
#include <hip/hip_runtime.h>
#include <hip/hip_bf16.h>
#include <stdint.h>

// Problem constants (fixed by setup_inputs)
#define BATCH 8
#define NN    2048
#define FF    128      // IN_F
#define OUTF  256
#define C14   512      // 4*FF (P1..P4 feature blocks)

typedef unsigned short u16;
typedef u16  u16x8 __attribute__((ext_vector_type(8)));
typedef float f32x4 __attribute__((ext_vector_type(4)));

__device__ __forceinline__ u16 f2bf(float x) {
    union { float f; uint32_t u; } v; v.f = x;
    uint32_t r = v.u + 0x7FFFu + ((v.u >> 16) & 1u);   // round-to-nearest-even
    return (u16)(r >> 16);
}
__device__ __forceinline__ uint32_t pack2(float a, float b) {
    return (uint32_t)f2bf(a) | ((uint32_t)f2bf(b) << 16);
}

// MFMA via inline asm: sidesteps builtin operand-type (v8i16 vs v8bf16) ambiguity.
// D,A,B,C order per cdna4_isa.md §10; gfx950 unified file allows all-VGPR C/D.
__device__ __forceinline__ f32x4 mfma_bf16(u16x8 a, u16x8 b, f32x4 c) {
    asm("v_mfma_f32_16x16x32_bf16 %0, %1, %2, %0" : "+v"(c) : "v"(a), "v"(b));
    return c;
}

// ---------------- d = rsqrt(1 + rowsum(adj)) ----------------
__global__ __launch_bounds__(256) void k_rowsum(const float* __restrict__ adj,
                                                float* __restrict__ dv) {
    size_t row = blockIdx.x;
    const float4* p = (const float4*)(adj + row * NN);
    int t = threadIdx.x;
    float4 v0 = p[t], v1 = p[t + 256];
    float s = v0.x + v0.y + v0.z + v0.w + v1.x + v1.y + v1.z + v1.w;
    #pragma unroll
    for (int off = 32; off > 0; off >>= 1) s += __shfl_down(s, off);
    __shared__ float r4[4];
    if ((t & 63) == 0) r4[t >> 6] = s;
    __syncthreads();
    if (t == 0) dv[row] = rsqrtf(r4[0] + r4[1] + r4[2] + r4[3] + 1.0f);
}

// ---------------- xT[b][f][m] bf16 (transpose + cast) ----------------
__global__ __launch_bounds__(256) void k_xprep(const float* __restrict__ x,
                                               u16* __restrict__ xT) {
    __shared__ u16 tile[FF][66];   // +2 ushort pad -> conflict-free
    int b = blockIdx.x >> 5, mt = blockIdx.x & 31;   // 64 m-rows per block
    const float* xb = x + ((size_t)(b * NN) + mt * 64) * FF;
    int t = threadIdx.x;
    #pragma unroll
    for (int i = 0; i < 32; ++i) {
        int idx = i * 256 + t;
        int ml = idx >> 7, f = idx & 127;
        tile[f][ml] = f2bf(xb[idx]);
    }
    __syncthreads();
    u16* xb2 = xT + (size_t)b * FF * NN + mt * 64;
    #pragma unroll
    for (int i = 0; i < 16; ++i) {
        int p = i * 256 + t;
        int f = p >> 5, mp = p & 31;
        uint32_t v = (uint32_t)tile[f][2 * mp] | ((uint32_t)tile[f][2 * mp + 1] << 16);
        *(uint32_t*)(xb2 + (size_t)f * NN + 2 * mp) = v;
    }
}

// ---------------- per-(b, m-chunk) partial colsums of x ----------------
__global__ __launch_bounds__(256) void k_xpart(const float* __restrict__ x,
                                               float* __restrict__ part) {
    int b = blockIdx.x >> 4, j = blockIdx.x & 15;    // 128 m per block
    int t = threadIdx.x, f = t & 127, half = t >> 7;
    const float* xb = x + ((size_t)b * NN + j * 128 + half * 64) * FF;
    float s = 0.f;
    for (int m = 0; m < 64; ++m) s += xb[m * FF + f];
    __shared__ float red[256];
    red[t] = s; __syncthreads();
    if (t < 128) part[(size_t)blockIdx.x * FF + t] = red[t] + red[t + 128];
}

// ---------------- W_eff = w_out @ w_heads_flat  (per-o block) ----------------
__global__ __launch_bounds__(256) void k_weff(const float* __restrict__ wh,
                                              const float* __restrict__ wo,
                                              float* __restrict__ weff0,
                                              u16* __restrict__ w14) {
    int o = blockIdx.x, t = threadIdx.x;
    __shared__ float wrow[256];
    wrow[t] = wo[o * 256 + t];
    __syncthreads();
    int c2 = (t < 128) ? (t + 512) : 639;
    float s0 = 0.f, s1 = 0.f, s2 = 0.f;
    for (int i = 0; i < 256; ++i) {
        float w = wrow[i];
        const float* row = wh + (size_t)i * 640;
        s0 = fmaf(w, row[t], s0);
        s1 = fmaf(w, row[t + 256], s1);
        s2 = fmaf(w, row[c2], s2);
    }
    if (t < 128) weff0[o * 128 + t] = s0;
    else         w14[(size_t)o * C14 + (t - 128)] = f2bf(s0);
    w14[(size_t)o * C14 + (t + 128)] = f2bf(s1);
    if (t < 128) w14[(size_t)o * C14 + (t + 384)] = f2bf(s2);
}

// ---------------- cb[b][o] = b_out + w_out@bh + Weff0 @ colsum(x_b) ----------------
__global__ __launch_bounds__(256) void k_cb(const float* __restrict__ part,
                                            const float* __restrict__ weff0,
                                            const float* __restrict__ wo,
                                            const float* __restrict__ bh,
                                            const float* __restrict__ bo,
                                            float* __restrict__ cb) {
    int b = blockIdx.x, t = threadIdx.x;
    __shared__ float cs[128];
    __shared__ float bhl[256];
    if (t < 128) {
        float s = 0.f;
        for (int j = 0; j < 16; ++j) s += part[(size_t)(b * 16 + j) * FF + t];
        cs[t] = s;
    }
    bhl[t] = bh[t];
    __syncthreads();
    float s = bo[t];
    for (int i = 0; i < 256; ++i) s = fmaf(wo[(size_t)t * 256 + i], bhl[i], s);
    for (int f = 0; f < 128; ++f) s = fmaf(weff0[t * 128 + f], cs[f], s);
    cb[b * 256 + t] = s;
}

// ---------------- MAIN: prop14[b][n][k-1][f] = sum_m P_k(L[n,m]) x[m,f] ----------------
// 512 blocks = 8 batches x 64 row-tiles of BM=32. 4 waves; wave w owns poly P_{w+1}
// (32x128 out, acc 2x8 f32x4). BK=64. XOR-swizzled LDS tiles (T2) for b128 frag reads.
__global__ __launch_bounds__(256, 2) void k_main(const float* __restrict__ adj,
                                                 const float* __restrict__ dvec,
                                                 const u16* __restrict__ xT,
                                                 u16* __restrict__ prop) {
    __shared__ __align__(16) u16 Abuf[4 * 32 * 64];   // 4 polys x [32][64], swizzled, 16KB
    __shared__ __align__(16) u16 Bbuf[FF * 64];       // xT tile [128 f][64 m], swizzled, 16KB
    __shared__ float dn_l[32];

    int tid = threadIdx.x, lane = tid & 63, wv = tid >> 6;
    int bb = blockIdx.x >> 6, rt = blockIdx.x & 63;
    const float* adjb = adj + (size_t)bb * NN * NN + (size_t)(rt * 32) * NN;
    const u16* xTb = xT + (size_t)bb * FF * NN;
    if (tid < 32) dn_l[tid] = dvec[bb * NN + rt * 32 + tid];
    __syncthreads();

    int mp = tid & 31;             // m-pair index within a row (A-gen)
    f32x4 acc[2][8];
    #pragma unroll
    for (int mi = 0; mi < 2; ++mi)
        #pragma unroll
        for (int ni = 0; ni < 8; ++ni) acc[mi][ni] = (f32x4){0.f, 0.f, 0.f, 0.f};

    for (int ks = 0; ks < NN / 64; ++ks) {
        int mbase = ks * 64;
        // ---- stage B: xT [128][64] -> LDS (swizzled), reg-staged b128 ----
        #pragma unroll
        for (int it = 0; it < 4; ++it) {
            int ci = it * 256 + tid;
            int f = ci >> 3, c = ci & 7;
            u16x8 v = *(const u16x8*)(xTb + (size_t)f * NN + mbase + c * 8);
            *(u16x8*)((char*)Bbuf + f * 128 + ((c ^ (f & 7)) << 4)) = v;
        }
        // ---- stage A: adj -> L -> P1..P4 (fp32) -> bf16 pairs -> 4 LDS tiles ----
        float2 dmv = *(const float2*)(dvec + bb * NN + mbase + 2 * mp);
        #pragma unroll
        for (int i = 0; i < 4; ++i) {
            int r = i * 8 + (tid >> 5);
            int ng = rt * 32 + r;
            float2 av = *(const float2*)(adjb + (size_t)r * NN + mbase + 2 * mp);
            float dnv = dn_l[r];
            float a0 = av.x + ((mbase + 2 * mp)     == ng ? 1.f : 0.f);
            float a1 = av.y + ((mbase + 2 * mp + 1) == ng ? 1.f : 0.f);
            float L0 = a0 * dnv * dmv.x, L1 = a1 * dnv * dmv.y;
            float p2a = fmaf(1.5f * L0, L0, -0.5f);
            float p2b = fmaf(1.5f * L1, L1, -0.5f);
            float p3a = L0 * fmaf(1.66666667f, p2a, -0.66666667f);
            float p3b = L1 * fmaf(1.66666667f, p2b, -0.66666667f);
            float p4a = fmaf(1.75f * L0, p3a, -0.75f * p2a);
            float p4b = fmaf(1.75f * L1, p3b, -0.75f * p2b);
            uint32_t byteoff = (uint32_t)(r * 128 + (((mp * 4) ^ ((r & 7) << 4))));
            char* base = (char*)Abuf + byteoff;
            *(uint32_t*)(base)          = pack2(L0, L1);
            *(uint32_t*)(base + 4096)   = pack2(p2a, p2b);
            *(uint32_t*)(base + 8192)   = pack2(p3a, p3b);
            *(uint32_t*)(base + 12288)  = pack2(p4a, p4b);
        }
        __syncthreads();
        // ---- compute: wave wv consumes poly tile wv + shared x tile ----
        const char* Ab = (const char*)Abuf + (wv << 12);
        const char* Bb = (const char*)Bbuf;
        #pragma unroll
        for (int kk = 0; kk < 2; ++kk) {
            int ch = (kk << 2) + (lane >> 4);
            u16x8 af[2];
            #pragma unroll
            for (int mi = 0; mi < 2; ++mi) {
                int row = mi * 16 + (lane & 15);
                af[mi] = *(const u16x8*)(Ab + row * 128 + ((ch ^ (row & 7)) << 4));
            }
            #pragma unroll
            for (int ni = 0; ni < 8; ++ni) {
                int fr = ni * 16 + (lane & 15);
                u16x8 bf = *(const u16x8*)(Bb + fr * 128 + ((ch ^ (fr & 7)) << 4));
                acc[0][ni] = mfma_bf16(af[0], bf, acc[0][ni]);
                acc[1][ni] = mfma_bf16(af[1], bf, acc[1][ni]);
            }
        }
        __syncthreads();
    }
    // MFMA -> VALU hazard guard before epilogue conversions
    asm volatile("s_nop 15\n\ts_nop 15");
    u16* pb = prop + ((size_t)bb * NN + rt * 32) * C14 + wv * 128;
    #pragma unroll
    for (int mi = 0; mi < 2; ++mi)
        #pragma unroll
        for (int ni = 0; ni < 8; ++ni) {
            int col = ni * 16 + (lane & 15);
            #pragma unroll
            for (int r4 = 0; r4 < 4; ++r4) {
                int row = mi * 16 + ((lane >> 4) << 2) + r4;  // C/D: col=lane&15, row=(lane>>4)*4+reg
                pb[(size_t)row * C14 + col] = f2bf(acc[mi][ni][r4]);
            }
        }
}

// ---------------- FINAL: out = prop14 @ W14^T + cb[b] ----------------
// 512 blocks x 32 rows; BN=256 (wave w owns 64 o-cols); BK=64, 8 K-steps.
__global__ __launch_bounds__(256, 2) void k_final(const u16* __restrict__ prop,
                                                  const u16* __restrict__ w14,
                                                  const float* __restrict__ cb,
                                                  float* __restrict__ out) {
    __shared__ __align__(16) u16 Abuf[32 * 64];    // 4KB swizzled
    __shared__ __align__(16) u16 Bbuf[256 * 64];   // 32KB swizzled
    int tid = threadIdx.x, lane = tid & 63, wv = tid >> 6;
    int rt = blockIdx.x, bb = rt >> 6;
    const u16* Ap = prop + (size_t)rt * 32 * C14;

    f32x4 acc[2][4];
    #pragma unroll
    for (int mi = 0; mi < 2; ++mi)
        #pragma unroll
        for (int ni = 0; ni < 4; ++ni) acc[mi][ni] = (f32x4){0.f, 0.f, 0.f, 0.f};

    for (int ks = 0; ks < 8; ++ks) {
        {   // stage A: [32][64]
            int r = tid >> 3, c = tid & 7;
            u16x8 v = *(const u16x8*)(Ap + (size_t)r * C14 + ks * 64 + c * 8);
            *(u16x8*)((char*)Abuf + r * 128 + ((c ^ (r & 7)) << 4)) = v;
        }
        #pragma unroll
        for (int it = 0; it < 8; ++it) {   // stage B: w14 [256][64]
            int ci = it * 256 + tid;
            int o = ci >> 3, c = ci & 7;
            u16x8 v = *(const u16x8*)(w14 + (size_t)o * C14 + ks * 64 + c * 8);
            *(u16x8*)((char*)Bbuf + o * 128 + ((c ^ (o & 7)) << 4)) = v;
        }
        __syncthreads();
        #pragma unroll
        for (int kk = 0; kk < 2; ++kk) {
            int ch = (kk << 2) + (lane >> 4);
            u16x8 af[2];
            #pragma unroll
            for (int mi = 0; mi < 2; ++mi) {
                int row = mi * 16 + (lane & 15);
                af[mi] = *(const u16x8*)((char*)Abuf + row * 128 + ((ch ^ (row & 7)) << 4));
            }
            #pragma unroll
            for (int ni = 0; ni < 4; ++ni) {
                int o = wv * 64 + ni * 16 + (lane & 15);
                u16x8 bf = *(const u16x8*)((char*)Bbuf + o * 128 + ((ch ^ (o & 7)) << 4));
                acc[0][ni] = mfma_bf16(af[0], bf, acc[0][ni]);
                acc[1][ni] = mfma_bf16(af[1], bf, acc[1][ni]);
            }
        }
        __syncthreads();
    }
    asm volatile("s_nop 15\n\ts_nop 15");
    float* ob = out + (size_t)rt * 32 * OUTF;
    const float* cbb = cb + bb * OUTF + wv * 64;
    #pragma unroll
    for (int mi = 0; mi < 2; ++mi)
        #pragma unroll
        for (int ni = 0; ni < 4; ++ni) {
            int col = ni * 16 + (lane & 15);
            float cv = cbb[col];
            #pragma unroll
            for (int r4 = 0; r4 < 4; ++r4) {
                int row = mi * 16 + ((lane >> 4) << 2) + r4;
                ob[(size_t)row * OUTF + wv * 64 + col] = acc[mi][ni][r4] + cv;
            }
        }
}

extern "C" void kernel_launch(void* const* d_in, const int* in_sizes, int n_in,
                              void* d_out, int out_size, void* d_ws, size_t ws_size,
                              hipStream_t stream) {
    const float* x   = (const float*)d_in[0];
    const float* adj = (const float*)d_in[1];
    const float* wh  = (const float*)d_in[2];   // [4][64][640] -> flat [256][640]
    const float* bh  = (const float*)d_in[3];   // [256]
    const float* wo  = (const float*)d_in[4];   // [256][256]
    const float* bo  = (const float*)d_in[5];   // [256]

    char* p = (char*)d_ws;
    float* dvec  = (float*)p;  p += (size_t)BATCH * NN * 4;            // 64 KB
    u16*   xT    = (u16*)p;    p += (size_t)BATCH * FF * NN * 2;       // 4 MB
    float* part  = (float*)p;  p += (size_t)128 * FF * 4;              // 64 KB
    float* weff0 = (float*)p;  p += (size_t)OUTF * FF * 4;             // 128 KB
    u16*   w14   = (u16*)p;    p += (size_t)OUTF * C14 * 2;            // 256 KB
    float* cbv   = (float*)p;  p += (size_t)BATCH * OUTF * 4;          // 8 KB
    u16*   prop  = (u16*)p;    p += (size_t)BATCH * NN * C14 * 2;      // 16.75 MB

    k_rowsum<<<dim3(BATCH * NN), dim3(256), 0, stream>>>(adj, dvec);
    k_xprep <<<dim3(256),        dim3(256), 0, stream>>>(x, xT);
    k_xpart <<<dim3(128),        dim3(256), 0, stream>>>(x, part);
    k_weff  <<<dim3(256),        dim3(256), 0, stream>>>(wh, wo, weff0, w14);
    k_cb    <<<dim3(BATCH),      dim3(256), 0, stream>>>(part, weff0, wo, bh, bo, cbv);
    k_main  <<<dim3(512),        dim3(256), 0, stream>>>(adj, dvec, xT, prop);
    k_final <<<dim3(512),        dim3(256), 0, stream>>>(prop, w14, cbv, (float*)d_out);
}

// Round 3
// 304.827 us; speedup vs baseline: 1.0328x; 1.0328x over previous
//
#include <hip/hip_runtime.h>
#include <hip/hip_bf16.h>
#include <stdint.h>

// Problem constants (fixed by setup_inputs)
#define BATCH 8
#define NN    2048
#define FF    128      // IN_F
#define OUTF  256
#define C14   512      // 4*FF (P1..P4 feature blocks)

typedef unsigned short u16;
typedef u16  u16x8 __attribute__((ext_vector_type(8)));
typedef float f32x4 __attribute__((ext_vector_type(4)));

__device__ __forceinline__ u16 f2bf(float x) {
    union { float f; uint32_t u; } v; v.f = x;
    uint32_t r = v.u + 0x7FFFu + ((v.u >> 16) & 1u);   // RNE
    return (u16)(r >> 16);
}
// packed f32x2 -> bf16x2 via hip header (compiler emits cvt_pk path)
__device__ __forceinline__ uint32_t pk2(float a, float b) {
    __hip_bfloat162 h = __float22bfloat162_rn(make_float2(a, b));
    union { __hip_bfloat162 h; uint32_t u; } cv; cv.h = h; return cv.u;
}

__device__ __forceinline__ f32x4 mfma_bf16(u16x8 a, u16x8 b, f32x4 c) {
    asm("v_mfma_f32_16x16x32_bf16 %0, %1, %2, %0" : "+v"(c) : "v"(a), "v"(b));
    return c;
}

// ---------------- d = rsqrt(1 + rowsum(adj)) ----------------
__global__ __launch_bounds__(256) void k_rowsum(const float* __restrict__ adj,
                                                float* __restrict__ dv) {
    size_t row = blockIdx.x;
    const float4* p = (const float4*)(adj + row * NN);
    int t = threadIdx.x;
    float4 v0 = p[t], v1 = p[t + 256];
    float s = v0.x + v0.y + v0.z + v0.w + v1.x + v1.y + v1.z + v1.w;
    #pragma unroll
    for (int off = 32; off > 0; off >>= 1) s += __shfl_down(s, off);
    __shared__ float r4[4];
    if ((t & 63) == 0) r4[t >> 6] = s;
    __syncthreads();
    if (t == 0) dv[row] = rsqrtf(r4[0] + r4[1] + r4[2] + r4[3] + 1.0f);
}

// ---------------- xT[b][f][m] bf16 (transpose + cast) + partial colsums ----------------
__global__ __launch_bounds__(256) void k_xprep(const float* __restrict__ x,
                                               u16* __restrict__ xT,
                                               float* __restrict__ part) {
    __shared__ u16 tile[FF][66];   // +2 ushort pad -> conflict-free
    __shared__ float red[256];
    int b = blockIdx.x >> 5, mt = blockIdx.x & 31;   // 64 m-rows per block
    const float* xb = x + ((size_t)(b * NN) + mt * 64) * FF;
    int t = threadIdx.x;
    float s = 0.f;
    #pragma unroll
    for (int i = 0; i < 32; ++i) {
        int idx = i * 256 + t;
        int ml = idx >> 7, f = idx & 127;   // f == t&127 for all i
        float v = xb[idx];
        tile[f][ml] = f2bf(v);
        s += v;
    }
    red[t] = s;
    __syncthreads();
    u16* xb2 = xT + (size_t)b * FF * NN + mt * 64;
    #pragma unroll
    for (int i = 0; i < 16; ++i) {
        int p = i * 256 + t;
        int f = p >> 5, mp = p & 31;
        uint32_t v = (uint32_t)tile[f][2 * mp] | ((uint32_t)tile[f][2 * mp + 1] << 16);
        *(uint32_t*)(xb2 + (size_t)f * NN + 2 * mp) = v;
    }
    if (t < 128) part[(size_t)blockIdx.x * FF + t] = red[t] + red[t + 128];
}

// ---------------- W_eff = w_out @ w_heads_flat  (per-o block) ----------------
__global__ __launch_bounds__(256) void k_weff(const float* __restrict__ wh,
                                              const float* __restrict__ wo,
                                              float* __restrict__ weff0,
                                              u16* __restrict__ w14) {
    int o = blockIdx.x, t = threadIdx.x;
    __shared__ float wrow[256];
    wrow[t] = wo[o * 256 + t];
    __syncthreads();
    int c2 = (t < 128) ? (t + 512) : 639;
    float s0 = 0.f, s1 = 0.f, s2 = 0.f;
    for (int i = 0; i < 256; ++i) {
        float w = wrow[i];
        const float* row = wh + (size_t)i * 640;
        s0 = fmaf(w, row[t], s0);
        s1 = fmaf(w, row[t + 256], s1);
        s2 = fmaf(w, row[c2], s2);
    }
    if (t < 128) weff0[o * 128 + t] = s0;
    else         w14[(size_t)o * C14 + (t - 128)] = f2bf(s0);
    w14[(size_t)o * C14 + (t + 128)] = f2bf(s1);
    if (t < 128) w14[(size_t)o * C14 + (t + 384)] = f2bf(s2);
}

// ---------------- cb[b][o] = b_out + w_out@bh + Weff0 @ colsum(x_b) ----------------
__global__ __launch_bounds__(256) void k_cb(const float* __restrict__ part,
                                            const float* __restrict__ weff0,
                                            const float* __restrict__ wo,
                                            const float* __restrict__ bh,
                                            const float* __restrict__ bo,
                                            float* __restrict__ cb) {
    int b = blockIdx.x, t = threadIdx.x;
    __shared__ float cs[128];
    __shared__ float bhl[256];
    if (t < 128) {
        float s = 0.f;
        for (int j = 0; j < 32; ++j) s += part[(size_t)(b * 32 + j) * FF + t];
        cs[t] = s;
    }
    bhl[t] = bh[t];
    __syncthreads();
    float s = bo[t];
    for (int i = 0; i < 256; ++i) s = fmaf(wo[(size_t)t * 256 + i], bhl[i], s);
    for (int f = 0; f < 128; ++f) s = fmaf(weff0[t * 128 + f], cs[f], s);
    cb[b * 256 + t] = s;
}

// ================= MAIN (pipelined) =================
// prop14[b][n][k-1][f] = sum_m P_k(L[n,m]) x[m,f]
// 512 blocks = 8 batches x 64 row-tiles of BM=32. 4 waves; wave w owns poly P_{w+1}.
// Double-buffered LDS, ONE barrier per K-step; regs prefetched one step ahead,
// global loads issued one step earlier still (T3 2-phase + T14 issue-early).
struct MRegs { u16x8 bv[4]; f32x4 av[2]; f32x4 dmv; };

__device__ __forceinline__ void m_prefetch(MRegs& R, const u16* xTb, const float* adjb,
                                           const float* dvb, int mbase, int tid) {
    #pragma unroll
    for (int it = 0; it < 4; ++it) {
        int ci = it * 256 + tid; int f = ci >> 3, c = ci & 7;
        R.bv[it] = *(const u16x8*)(xTb + (size_t)f * NN + mbase + c * 8);
    }
    int q = tid & 15;
    R.dmv = *(const f32x4*)(dvb + mbase + q * 4);
    #pragma unroll
    for (int i = 0; i < 2; ++i) {
        int r = i * 16 + (tid >> 4);
        R.av[i] = *(const f32x4*)(adjb + (size_t)r * NN + mbase + q * 4);
    }
}

__device__ __forceinline__ void m_commit(const MRegs& R, u16* Ab, u16* Bb,
                                         const float* dn_l, int mbase, int rt, int tid) {
    #pragma unroll
    for (int it = 0; it < 4; ++it) {
        int ci = it * 256 + tid; int f = ci >> 3, c = ci & 7;
        *(u16x8*)((char*)Bb + f * 128 + ((c ^ (f & 7)) << 4)) = R.bv[it];
    }
    int q = tid & 15;
    #pragma unroll
    for (int i = 0; i < 2; ++i) {
        int r = i * 16 + (tid >> 4);
        int ng = rt * 32 + r - mbase - q * 4;   // diagonal hits when j == ng
        float dnv = dn_l[r];
        float L[4], P2[4], P3[4], P4[4];
        #pragma unroll
        for (int j = 0; j < 4; ++j) {
            float a = R.av[i][j] + ((j == ng) ? 1.f : 0.f);
            L[j]  = a * dnv * R.dmv[j];
            P2[j] = fmaf(1.5f * L[j], L[j], -0.5f);
            P3[j] = L[j] * fmaf(1.66666667f, P2[j], -0.66666667f);
            P4[j] = fmaf(1.75f * L[j], P3[j], -0.75f * P2[j]);
        }
        char* base = (char*)Ab + (uint32_t)(r * 128 + ((q * 8) ^ ((r & 7) << 4)));
        *(uint2*)(base)         = make_uint2(pk2(L[0],  L[1]),  pk2(L[2],  L[3]));
        *(uint2*)(base + 4096)  = make_uint2(pk2(P2[0], P2[1]), pk2(P2[2], P2[3]));
        *(uint2*)(base + 8192)  = make_uint2(pk2(P3[0], P3[1]), pk2(P3[2], P3[3]));
        *(uint2*)(base + 12288) = make_uint2(pk2(P4[0], P4[1]), pk2(P4[2], P4[3]));
    }
}

__device__ __forceinline__ void m_mfma(const u16* A, const u16* B, int lane, f32x4 acc[2][8]) {
    #pragma unroll
    for (int kk = 0; kk < 2; ++kk) {
        int ch = (kk << 2) + (lane >> 4);
        u16x8 af[2];
        #pragma unroll
        for (int mi = 0; mi < 2; ++mi) {
            int row = mi * 16 + (lane & 15);
            af[mi] = *(const u16x8*)((const char*)A + row * 128 + ((ch ^ (row & 7)) << 4));
        }
        #pragma unroll
        for (int ni = 0; ni < 8; ++ni) {
            int fr = ni * 16 + (lane & 15);
            u16x8 bf = *(const u16x8*)((const char*)B + fr * 128 + ((ch ^ (fr & 7)) << 4));
            acc[0][ni] = mfma_bf16(af[0], bf, acc[0][ni]);
            acc[1][ni] = mfma_bf16(af[1], bf, acc[1][ni]);
        }
    }
}

__global__ __launch_bounds__(256, 2) void k_main(const float* __restrict__ adj,
                                                 const float* __restrict__ dvec,
                                                 const u16* __restrict__ xT,
                                                 u16* __restrict__ prop) {
    __shared__ __align__(16) u16 Abuf[2][4 * 32 * 64];   // 2 x 16KB (4 poly tiles)
    __shared__ __align__(16) u16 Bbuf[2][FF * 64];       // 2 x 16KB
    __shared__ float dn_l[32];

    int tid = threadIdx.x, lane = tid & 63, wv = tid >> 6;
    int bb = blockIdx.x >> 6, rt = blockIdx.x & 63;
    const float* adjb = adj + (size_t)bb * NN * NN + (size_t)(rt * 32) * NN;
    const float* dvb = dvec + bb * NN;
    const u16* xTb = xT + (size_t)bb * FF * NN;

    f32x4 acc[2][8];
    #pragma unroll
    for (int mi = 0; mi < 2; ++mi)
        #pragma unroll
        for (int ni = 0; ni < 8; ++ni) acc[mi][ni] = (f32x4){0.f, 0.f, 0.f, 0.f};

    MRegs R0, R1;
    if (tid < 32) dn_l[tid] = dvec[bb * NN + rt * 32 + tid];
    m_prefetch(R0, xTb, adjb, dvb, 0, tid);
    __syncthreads();                       // dn_l ready
    m_commit(R0, Abuf[0], Bbuf[0], dn_l, 0, rt, tid);
    m_prefetch(R1, xTb, adjb, dvb, 64, tid);
    __syncthreads();                       // buf0 ready

    for (int ks = 0; ks < 32; ks += 2) {
        // even step: MFMA buf0 (step ks); commit R1->buf1 (ks+1); prefetch R0<-ks+2
        if (ks + 2 < 32) m_prefetch(R0, xTb, adjb, dvb, (ks + 2) * 64, tid);
        m_commit(R1, Abuf[1], Bbuf[1], dn_l, (ks + 1) * 64, rt, tid);
        m_mfma((const u16*)Abuf[0] + wv * 2048, (const u16*)Bbuf[0], lane, acc);
        __syncthreads();
        // odd step: MFMA buf1 (ks+1); commit R0->buf0 (ks+2); prefetch R1<-ks+3
        if (ks + 3 < 32) m_prefetch(R1, xTb, adjb, dvb, (ks + 3) * 64, tid);
        if (ks + 2 < 32) m_commit(R0, Abuf[0], Bbuf[0], dn_l, (ks + 2) * 64, rt, tid);
        m_mfma((const u16*)Abuf[1] + wv * 2048, (const u16*)Bbuf[1], lane, acc);
        __syncthreads();
    }
    asm volatile("s_nop 15\n\ts_nop 15");   // MFMA->VALU hazard guard
    u16* pb = prop + ((size_t)bb * NN + rt * 32) * C14 + wv * 128;
    #pragma unroll
    for (int mi = 0; mi < 2; ++mi)
        #pragma unroll
        for (int ni = 0; ni < 8; ++ni) {
            int col = ni * 16 + (lane & 15);
            #pragma unroll
            for (int r4 = 0; r4 < 4; ++r4) {
                int row = mi * 16 + ((lane >> 4) << 2) + r4;
                pb[(size_t)row * C14 + col] = f2bf(acc[mi][ni][r4]);
            }
        }
}

// ================= FINAL (pipelined): out = prop14 @ W14^T + cb[b] =================
struct FRegs { u16x8 a; u16x8 b[8]; };

__device__ __forceinline__ void f_prefetch(FRegs& R, const u16* Ap, const u16* w14,
                                           int mb, int tid) {
    { int r = tid >> 3, c = tid & 7;
      R.a = *(const u16x8*)(Ap + (size_t)r * C14 + mb + c * 8); }
    #pragma unroll
    for (int it = 0; it < 8; ++it) {
        int ci = it * 256 + tid; int o = ci >> 3, c = ci & 7;
        R.b[it] = *(const u16x8*)(w14 + (size_t)o * C14 + mb + c * 8);
    }
}
__device__ __forceinline__ void f_commit(const FRegs& R, u16* FA, u16* FB, int tid) {
    { int r = tid >> 3, c = tid & 7;
      *(u16x8*)((char*)FA + r * 128 + ((c ^ (r & 7)) << 4)) = R.a; }
    #pragma unroll
    for (int it = 0; it < 8; ++it) {
        int ci = it * 256 + tid; int o = ci >> 3, c = ci & 7;
        *(u16x8*)((char*)FB + o * 128 + ((c ^ (o & 7)) << 4)) = R.b[it];
    }
}
__device__ __forceinline__ void f_mfma(const u16* FA, const u16* FB, int lane, int wv,
                                       f32x4 acc[2][4]) {
    #pragma unroll
    for (int kk = 0; kk < 2; ++kk) {
        int ch = (kk << 2) + (lane >> 4);
        u16x8 af[2];
        #pragma unroll
        for (int mi = 0; mi < 2; ++mi) {
            int row = mi * 16 + (lane & 15);
            af[mi] = *(const u16x8*)((const char*)FA + row * 128 + ((ch ^ (row & 7)) << 4));
        }
        #pragma unroll
        for (int ni = 0; ni < 4; ++ni) {
            int o = wv * 64 + ni * 16 + (lane & 15);
            u16x8 bf = *(const u16x8*)((const char*)FB + o * 128 + ((ch ^ (o & 7)) << 4));
            acc[0][ni] = mfma_bf16(af[0], bf, acc[0][ni]);
            acc[1][ni] = mfma_bf16(af[1], bf, acc[1][ni]);
        }
    }
}

__global__ __launch_bounds__(256, 2) void k_final(const u16* __restrict__ prop,
                                                  const u16* __restrict__ w14,
                                                  const float* __restrict__ cb,
                                                  float* __restrict__ out) {
    __shared__ __align__(16) u16 FA[2][32 * 64];    // 2 x 4KB
    __shared__ __align__(16) u16 FB[2][256 * 64];   // 2 x 32KB
    int tid = threadIdx.x, lane = tid & 63, wv = tid >> 6;
    int rt = blockIdx.x, bb = rt >> 6;
    const u16* Ap = prop + (size_t)rt * 32 * C14;

    f32x4 acc[2][4];
    #pragma unroll
    for (int mi = 0; mi < 2; ++mi)
        #pragma unroll
        for (int ni = 0; ni < 4; ++ni) acc[mi][ni] = (f32x4){0.f, 0.f, 0.f, 0.f};

    FRegs R0, R1;
    f_prefetch(R0, Ap, w14, 0, tid);
    f_commit(R0, FA[0], FB[0], tid);
    f_prefetch(R1, Ap, w14, 64, tid);
    __syncthreads();

    for (int ks = 0; ks < 8; ks += 2) {
        if (ks + 2 < 8) f_prefetch(R0, Ap, w14, (ks + 2) * 64, tid);
        f_commit(R1, FA[1], FB[1], tid);
        f_mfma(FA[0], FB[0], lane, wv, acc);
        __syncthreads();
        if (ks + 3 < 8) f_prefetch(R1, Ap, w14, (ks + 3) * 64, tid);
        if (ks + 2 < 8) f_commit(R0, FA[0], FB[0], tid);
        f_mfma(FA[1], FB[1], lane, wv, acc);
        __syncthreads();
    }
    asm volatile("s_nop 15\n\ts_nop 15");
    float* ob = out + (size_t)rt * 32 * OUTF;
    const float* cbb = cb + bb * OUTF + wv * 64;
    #pragma unroll
    for (int mi = 0; mi < 2; ++mi)
        #pragma unroll
        for (int ni = 0; ni < 4; ++ni) {
            int col = ni * 16 + (lane & 15);
            float cv = cbb[col];
            #pragma unroll
            for (int r4 = 0; r4 < 4; ++r4) {
                int row = mi * 16 + ((lane >> 4) << 2) + r4;
                ob[(size_t)row * OUTF + wv * 64 + col] = acc[mi][ni][r4] + cv;
            }
        }
}

extern "C" void kernel_launch(void* const* d_in, const int* in_sizes, int n_in,
                              void* d_out, int out_size, void* d_ws, size_t ws_size,
                              hipStream_t stream) {
    const float* x   = (const float*)d_in[0];
    const float* adj = (const float*)d_in[1];
    const float* wh  = (const float*)d_in[2];   // [4][64][640] -> flat [256][640]
    const float* bh  = (const float*)d_in[3];   // [256]
    const float* wo  = (const float*)d_in[4];   // [256][256]
    const float* bo  = (const float*)d_in[5];   // [256]

    char* p = (char*)d_ws;
    float* dvec  = (float*)p;  p += (size_t)BATCH * NN * 4;            // 64 KB
    u16*   xT    = (u16*)p;    p += (size_t)BATCH * FF * NN * 2;       // 4 MB
    float* part  = (float*)p;  p += (size_t)256 * FF * 4;              // 128 KB
    float* weff0 = (float*)p;  p += (size_t)OUTF * FF * 4;             // 128 KB
    u16*   w14   = (u16*)p;    p += (size_t)OUTF * C14 * 2;            // 256 KB
    float* cbv   = (float*)p;  p += (size_t)BATCH * OUTF * 4;          // 8 KB
    u16*   prop  = (u16*)p;    p += (size_t)BATCH * NN * C14 * 2;      // 16.75 MB

    k_rowsum<<<dim3(BATCH * NN), dim3(256), 0, stream>>>(adj, dvec);
    k_xprep <<<dim3(256),        dim3(256), 0, stream>>>(x, xT, part);
    k_weff  <<<dim3(256),        dim3(256), 0, stream>>>(wh, wo, weff0, w14);
    k_cb    <<<dim3(BATCH),      dim3(256), 0, stream>>>(part, weff0, wo, bh, bo, cbv);
    k_main  <<<dim3(512),        dim3(256), 0, stream>>>(adj, dvec, xT, prop);
    k_final <<<dim3(512),        dim3(256), 0, stream>>>(prop, w14, cbv, (float*)d_out);
}

// Round 6
// 300.658 us; speedup vs baseline: 1.0471x; 1.0139x over previous
//
#include <hip/hip_runtime.h>
#include <hip/hip_bf16.h>
#include <stdint.h>

#define BATCH 8
#define NN    2048
#define FF    128      // IN_F
#define OUTF  256
#define C14   512      // 4*FF (P1..P4 feature blocks)

typedef unsigned short u16;
typedef u16  u16x8 __attribute__((ext_vector_type(8)));
typedef float f32x4 __attribute__((ext_vector_type(4)));

__device__ __forceinline__ u16 f2bf(float x) {
    union { float f; uint32_t u; } v; v.f = x;
    uint32_t r = v.u + 0x7FFFu + ((v.u >> 16) & 1u);   // RNE
    return (u16)(r >> 16);
}
__device__ __forceinline__ uint32_t pk2(float a, float b) {
    __hip_bfloat162 h = __float22bfloat162_rn(make_float2(a, b));
    union { __hip_bfloat162 h; uint32_t u; } cv; cv.h = h; return cv.u;
}
__device__ __forceinline__ f32x4 mfma_bf16(u16x8 a, u16x8 b, f32x4 c) {
    asm("v_mfma_f32_16x16x32_bf16 %0, %1, %2, %0" : "+v"(c) : "v"(a), "v"(b));
    return c;
}

// ---------------- d = rsqrt(1 + rowsum(adj)) ----------------
__global__ __launch_bounds__(256) void k_rowsum(const float* __restrict__ adj,
                                                float* __restrict__ dv) {
    size_t row = blockIdx.x;
    const float4* p = (const float4*)(adj + row * NN);
    int t = threadIdx.x;
    float4 v0 = p[t], v1 = p[t + 256];
    float s = v0.x + v0.y + v0.z + v0.w + v1.x + v1.y + v1.z + v1.w;
    #pragma unroll
    for (int off = 32; off > 0; off >>= 1) s += __shfl_down(s, off);
    __shared__ float r4[4];
    if ((t & 63) == 0) r4[t >> 6] = s;
    __syncthreads();
    if (t == 0) dv[row] = rsqrtf(r4[0] + r4[1] + r4[2] + r4[3] + 1.0f);
}

// ------------- PREP (fused): blocks [0,256) xT transpose+cast+colsum; [256,512) W_eff -------------
__global__ __launch_bounds__(256) void k_prep(const float* __restrict__ x,
                                              u16* __restrict__ xT,
                                              float* __restrict__ part,
                                              const float* __restrict__ wh,
                                              const float* __restrict__ wo,
                                              float* __restrict__ weff0,
                                              u16* __restrict__ w14) {
    __shared__ u16 tile[FF][66];
    __shared__ float red[256];
    int t = threadIdx.x;
    if (blockIdx.x < 256) {
        int b = blockIdx.x >> 5, mt = blockIdx.x & 31;
        const float* xb = x + ((size_t)(b * NN) + mt * 64) * FF;
        float s = 0.f;
        #pragma unroll
        for (int i = 0; i < 32; ++i) {
            int idx = i * 256 + t;
            int ml = idx >> 7, f = idx & 127;
            float v = xb[idx];
            tile[f][ml] = f2bf(v);
            s += v;
        }
        red[t] = s;
        __syncthreads();
        u16* xb2 = xT + (size_t)b * FF * NN + mt * 64;
        #pragma unroll
        for (int i = 0; i < 16; ++i) {
            int p = i * 256 + t;
            int f = p >> 5, mp = p & 31;
            uint32_t v = (uint32_t)tile[f][2 * mp] | ((uint32_t)tile[f][2 * mp + 1] << 16);
            *(uint32_t*)(xb2 + (size_t)f * NN + 2 * mp) = v;
        }
        if (t < 128) part[(size_t)blockIdx.x * FF + t] = red[t] + red[t + 128];
    } else {
        int o = blockIdx.x - 256;
        red[t] = wo[o * 256 + t];
        __syncthreads();
        int c2 = (t < 128) ? (t + 512) : 639;
        float s0 = 0.f, s1 = 0.f, s2 = 0.f;
        for (int i = 0; i < 256; ++i) {
            float w = red[i];
            const float* row = wh + (size_t)i * 640;
            s0 = fmaf(w, row[t], s0);
            s1 = fmaf(w, row[t + 256], s1);
            s2 = fmaf(w, row[c2], s2);
        }
        if (t < 128) weff0[o * 128 + t] = s0;
        else         w14[(size_t)o * C14 + (t - 128)] = f2bf(s0);
        w14[(size_t)o * C14 + (t + 128)] = f2bf(s1);
        if (t < 128) w14[(size_t)o * C14 + (t + 384)] = f2bf(s2);
    }
}

// ---------------- cb[b][o] = b_out + w_out@bh + Weff0 @ colsum(x_b) ----------------
__global__ __launch_bounds__(256) void k_cb(const float* __restrict__ part,
                                            const float* __restrict__ weff0,
                                            const float* __restrict__ wo,
                                            const float* __restrict__ bh,
                                            const float* __restrict__ bo,
                                            float* __restrict__ cb) {
    int b = blockIdx.x, t = threadIdx.x;
    __shared__ float cs[128];
    __shared__ float bhl[256];
    if (t < 128) {
        float s = 0.f;
        for (int j = 0; j < 32; ++j) s += part[(size_t)(b * 32 + j) * FF + t];
        cs[t] = s;
    }
    bhl[t] = bh[t];
    __syncthreads();
    float s = bo[t];
    for (int i = 0; i < 256; ++i) s = fmaf(wo[(size_t)t * 256 + i], bhl[i], s);
    for (int f = 0; f < 128; ++f) s = fmaf(weff0[t * 128 + f], cs[f], s);
    cb[b * 256 + t] = s;
}

// ================= MERGED MAIN+FINAL (validated paths only) =================
// Phase A = Round-3 k_main (validated): prop tile accumulated in regs.
// Bridge: acc -> global prop tile (R3 epilogue, validated) -> __syncthreads().
// Phase C = Round-3 k_final (validated): restage from global (L1/L2-hot) + w14.
struct MRegs { u16x8 bv[4]; f32x4 av[2]; f32x4 dmv; };

__device__ __forceinline__ void m_prefetch(MRegs& R, const u16* xTb, const float* adjb,
                                           const float* dvb, int mbase, int tid) {
    #pragma unroll
    for (int it = 0; it < 4; ++it) {
        int ci = it * 256 + tid; int f = ci >> 3, c = ci & 7;
        R.bv[it] = *(const u16x8*)(xTb + (size_t)f * NN + mbase + c * 8);
    }
    int q = tid & 15;
    R.dmv = *(const f32x4*)(dvb + mbase + q * 4);
    #pragma unroll
    for (int i = 0; i < 2; ++i) {
        int r = i * 16 + (tid >> 4);
        R.av[i] = *(const f32x4*)(adjb + (size_t)r * NN + mbase + q * 4);
    }
}

__device__ __forceinline__ void m_commit(const MRegs& R, char* Ab, char* Bb,
                                         const float* dn_l, int mbase, int rt, int tid) {
    #pragma unroll
    for (int it = 0; it < 4; ++it) {
        int ci = it * 256 + tid; int f = ci >> 3, c = ci & 7;
        *(u16x8*)(Bb + f * 128 + ((c ^ (f & 7)) << 4)) = R.bv[it];
    }
    int q = tid & 15;
    #pragma unroll
    for (int i = 0; i < 2; ++i) {
        int r = i * 16 + (tid >> 4);
        int ng = rt * 32 + r - mbase - q * 4;
        float dnv = dn_l[r];
        float L[4], P2[4], P3[4], P4[4];
        #pragma unroll
        for (int j = 0; j < 4; ++j) {
            float a = R.av[i][j] + ((j == ng) ? 1.f : 0.f);
            L[j]  = a * dnv * R.dmv[j];
            P2[j] = fmaf(1.5f * L[j], L[j], -0.5f);
            P3[j] = L[j] * fmaf(1.66666667f, P2[j], -0.66666667f);
            P4[j] = fmaf(1.75f * L[j], P3[j], -0.75f * P2[j]);
        }
        char* base = Ab + (uint32_t)(r * 128 + ((q * 8) ^ ((r & 7) << 4)));
        *(uint2*)(base)         = make_uint2(pk2(L[0],  L[1]),  pk2(L[2],  L[3]));
        *(uint2*)(base + 4096)  = make_uint2(pk2(P2[0], P2[1]), pk2(P2[2], P2[3]));
        *(uint2*)(base + 8192)  = make_uint2(pk2(P3[0], P3[1]), pk2(P3[2], P3[3]));
        *(uint2*)(base + 12288) = make_uint2(pk2(P4[0], P4[1]), pk2(P4[2], P4[3]));
    }
}

__device__ __forceinline__ void m_mfma(const char* A, const char* B, int lane, f32x4 acc[2][8]) {
    #pragma unroll
    for (int kk = 0; kk < 2; ++kk) {
        int ch = (kk << 2) + (lane >> 4);
        u16x8 af[2];
        #pragma unroll
        for (int mi = 0; mi < 2; ++mi) {
            int row = mi * 16 + (lane & 15);
            af[mi] = *(const u16x8*)(A + row * 128 + ((ch ^ (row & 7)) << 4));
        }
        #pragma unroll
        for (int ni = 0; ni < 8; ++ni) {
            int fr = ni * 16 + (lane & 15);
            u16x8 bf = *(const u16x8*)(B + fr * 128 + ((ch ^ (fr & 7)) << 4));
            acc[0][ni] = mfma_bf16(af[0], bf, acc[0][ni]);
            acc[1][ni] = mfma_bf16(af[1], bf, acc[1][ni]);
        }
    }
}

struct FRegs { u16x8 a; u16x8 b[8]; };

__device__ __forceinline__ void f_prefetch(FRegs& R, const u16* Ap, const u16* w14,
                                           int mb, int tid) {
    { int r = tid >> 3, c = tid & 7;
      R.a = *(const u16x8*)(Ap + (size_t)r * C14 + mb + c * 8); }
    #pragma unroll
    for (int it = 0; it < 8; ++it) {
        int ci = it * 256 + tid; int o = ci >> 3, c = ci & 7;
        R.b[it] = *(const u16x8*)(w14 + (size_t)o * C14 + mb + c * 8);
    }
}
__device__ __forceinline__ void f_commit(const FRegs& R, char* FA, char* FB, int tid) {
    { int r = tid >> 3, c = tid & 7;
      *(u16x8*)(FA + r * 128 + ((c ^ (r & 7)) << 4)) = R.a; }
    #pragma unroll
    for (int it = 0; it < 8; ++it) {
        int ci = it * 256 + tid; int o = ci >> 3, c = ci & 7;
        *(u16x8*)(FB + o * 128 + ((c ^ (o & 7)) << 4)) = R.b[it];
    }
}
__device__ __forceinline__ void f_mfma(const char* FA, const char* FB, int lane, int wv,
                                       f32x4 acc[2][4]) {
    #pragma unroll
    for (int kk = 0; kk < 2; ++kk) {
        int ch = (kk << 2) + (lane >> 4);
        u16x8 af[2];
        #pragma unroll
        for (int mi = 0; mi < 2; ++mi) {
            int row = mi * 16 + (lane & 15);
            af[mi] = *(const u16x8*)(FA + row * 128 + ((ch ^ (row & 7)) << 4));
        }
        #pragma unroll
        for (int ni = 0; ni < 4; ++ni) {
            int o = wv * 64 + ni * 16 + (lane & 15);
            u16x8 bf = *(const u16x8*)(FB + o * 128 + ((ch ^ (o & 7)) << 4));
            acc[0][ni] = mfma_bf16(af[0], bf, acc[0][ni]);
            acc[1][ni] = mfma_bf16(af[1], bf, acc[1][ni]);
        }
    }
}

__global__ __launch_bounds__(256, 2) void k_mf(const float* __restrict__ adj,
                                               const float* __restrict__ dvec,
                                               const u16* __restrict__ xT,
                                               const u16* __restrict__ w14,
                                               const float* __restrict__ cb,
                                               u16* __restrict__ propg,
                                               float* __restrict__ out) {
    // Phase A layout: Ab0@0(16K) Ab1@16K Bb0@32K Bb1@48K
    // Phase C layout: FA0@0(4K) FA1@4K FB0@8K(32K) FB1@40K  -> 72KB total
    __shared__ __align__(16) char pool[73728];
    __shared__ float dn_l[32];

    int tid = threadIdx.x, lane = tid & 63, wv = tid >> 6;
    int bb = blockIdx.x >> 6, rt = blockIdx.x & 63;
    const float* adjb = adj + (size_t)bb * NN * NN + (size_t)(rt * 32) * NN;
    const float* dvb = dvec + bb * NN;
    const u16* xTb = xT + (size_t)bb * FF * NN;

    char* Ab0 = pool;            char* Ab1 = pool + 16384;
    char* Bb0 = pool + 32768;    char* Bb1 = pool + 49152;

    f32x4 acc[2][8];
    #pragma unroll
    for (int mi = 0; mi < 2; ++mi)
        #pragma unroll
        for (int ni = 0; ni < 8; ++ni) acc[mi][ni] = (f32x4){0.f, 0.f, 0.f, 0.f};

    MRegs R0, R1;
    if (tid < 32) dn_l[tid] = dvec[bb * NN + rt * 32 + tid];
    m_prefetch(R0, xTb, adjb, dvb, 0, tid);
    __syncthreads();
    m_commit(R0, Ab0, Bb0, dn_l, 0, rt, tid);
    m_prefetch(R1, xTb, adjb, dvb, 64, tid);
    __syncthreads();

    for (int ks = 0; ks < 32; ks += 2) {
        if (ks + 2 < 32) m_prefetch(R0, xTb, adjb, dvb, (ks + 2) * 64, tid);
        m_commit(R1, Ab1, Bb1, dn_l, (ks + 1) * 64, rt, tid);
        m_mfma(Ab0 + (wv << 12), Bb0, lane, acc);
        __syncthreads();
        if (ks + 3 < 32) m_prefetch(R1, xTb, adjb, dvb, (ks + 3) * 64, tid);
        if (ks + 2 < 32) m_commit(R0, Ab0, Bb0, dn_l, (ks + 2) * 64, rt, tid);
        m_mfma(Ab1 + (wv << 12), Bb1, lane, acc);
        __syncthreads();
    }
    asm volatile("s_nop 15\n\ts_nop 15");   // MFMA->VALU hazard guard

    // ---- Bridge: acc -> global prop tile (R3 k_main epilogue, validated) ----
    u16* pb = propg + (size_t)blockIdx.x * 32 * C14 + wv * 128;
    #pragma unroll
    for (int mi = 0; mi < 2; ++mi)
        #pragma unroll
        for (int ni = 0; ni < 8; ++ni) {
            int col = ni * 16 + (lane & 15);
            #pragma unroll
            for (int r4 = 0; r4 < 4; ++r4) {
                int row = mi * 16 + ((lane >> 4) << 2) + r4;
                pb[(size_t)row * C14 + col] = f2bf(acc[mi][ni][r4]);
            }
        }
    __syncthreads();   // block-scope visibility of prop tile (vmcnt drained)

    // ---- Phase C = R3 k_final (validated), restaging from hot prop tile ----
    const u16* Ap = propg + (size_t)blockIdx.x * 32 * C14;
    char* FA0 = pool;            char* FA1 = pool + 4096;
    char* FB0 = pool + 8192;     char* FB1 = pool + 40960;

    f32x4 facc[2][4];
    #pragma unroll
    for (int mi = 0; mi < 2; ++mi)
        #pragma unroll
        for (int ni = 0; ni < 4; ++ni) facc[mi][ni] = (f32x4){0.f, 0.f, 0.f, 0.f};

    FRegs F0, F1;
    f_prefetch(F0, Ap, w14, 0, tid);
    f_commit(F0, FA0, FB0, tid);
    f_prefetch(F1, Ap, w14, 64, tid);
    __syncthreads();

    for (int ks = 0; ks < 8; ks += 2) {
        if (ks + 2 < 8) f_prefetch(F0, Ap, w14, (ks + 2) * 64, tid);
        f_commit(F1, FA1, FB1, tid);
        f_mfma(FA0, FB0, lane, wv, facc);
        __syncthreads();
        if (ks + 3 < 8) f_prefetch(F1, Ap, w14, (ks + 3) * 64, tid);
        if (ks + 2 < 8) f_commit(F0, FA0, FB0, tid);
        f_mfma(FA1, FB1, lane, wv, facc);
        __syncthreads();
    }
    asm volatile("s_nop 15\n\ts_nop 15");
    float* ob = out + ((size_t)bb * NN + rt * 32) * OUTF;
    const float* cbb = cb + bb * OUTF + wv * 64;
    #pragma unroll
    for (int mi = 0; mi < 2; ++mi)
        #pragma unroll
        for (int ni = 0; ni < 4; ++ni) {
            int col = ni * 16 + (lane & 15);
            float cv = cbb[col];
            #pragma unroll
            for (int r4 = 0; r4 < 4; ++r4) {
                int row = mi * 16 + ((lane >> 4) << 2) + r4;
                ob[(size_t)row * OUTF + wv * 64 + col] = facc[mi][ni][r4] + cv;
            }
        }
}

extern "C" void kernel_launch(void* const* d_in, const int* in_sizes, int n_in,
                              void* d_out, int out_size, void* d_ws, size_t ws_size,
                              hipStream_t stream) {
    const float* x   = (const float*)d_in[0];
    const float* adj = (const float*)d_in[1];
    const float* wh  = (const float*)d_in[2];
    const float* bh  = (const float*)d_in[3];
    const float* wo  = (const float*)d_in[4];
    const float* bo  = (const float*)d_in[5];

    char* p = (char*)d_ws;
    float* dvec  = (float*)p;  p += (size_t)BATCH * NN * 4;
    u16*   xT    = (u16*)p;    p += (size_t)BATCH * FF * NN * 2;
    float* part  = (float*)p;  p += (size_t)256 * FF * 4;
    float* weff0 = (float*)p;  p += (size_t)OUTF * FF * 4;
    u16*   w14   = (u16*)p;    p += (size_t)OUTF * C14 * 2;
    float* cbv   = (float*)p;  p += (size_t)BATCH * OUTF * 4;
    u16*   propg = (u16*)p;    p += (size_t)BATCH * NN * C14 * 2;

    k_rowsum<<<dim3(BATCH * NN), dim3(256), 0, stream>>>(adj, dvec);
    k_prep  <<<dim3(512),        dim3(256), 0, stream>>>(x, xT, part, wh, wo, weff0, w14);
    k_cb    <<<dim3(BATCH),      dim3(256), 0, stream>>>(part, weff0, wo, bh, bo, cbv);
    k_mf    <<<dim3(512),        dim3(256), 0, stream>>>(adj, dvec, xT, w14, cbv, propg, (float*)d_out);
}